// Round 9
// baseline (2599.674 us; speedup 1.0000x reference)
//
#include <hip/hip_runtime.h>
#include <hip/hip_bf16.h>

#define N_NODES 200000
#define N_GRAPHS 1024
#define D 16
#define NEDGE 6400000

#define BNODES 256                 // nodes per bucket: bucket = dst >> 8
#define NBUK 782                   // ceil(200000/256)
#define NCH 800                    // edge chunks
#define ECHUNK 8000                // NEDGE / NCH (exact)
#define CAP 9216                   // bucket slab capacity (mean 8192, sd ~90 -> 11 sigma)

// ---- pA (fused R+L): reg-staged chunk sort. dst+src loaded ONCE (uint4, 8 edges/thr),
//      count+place from registers, coalesced run writeback into per-bucket slab.
//      Output: bucket-grouped, unsorted within bucket. ----
__global__ __launch_bounds__(1024) void pA(
        const int* __restrict__ srcR, const int* __restrict__ dstR,
        const int* __restrict__ srcL, const int* __restrict__ dstL,
        unsigned int* __restrict__ slabR, unsigned int* __restrict__ slabL,
        int* __restrict__ gcurR, int* __restrict__ gcurL) {
    const int* src = blockIdx.y ? srcL : srcR;
    const int* dst = blockIdx.y ? dstL : dstR;
    unsigned int* slab = blockIdx.y ? slabL : slabR;
    int* gcur = blockIdx.y ? gcurL : gcurR;

    __shared__ unsigned int stage[ECHUNK];      // 32 KB
    __shared__ unsigned short stageB[ECHUNK];   // 16 KB
    __shared__ int lh[NBUK];
    __shared__ int lcur[NBUK];
    __shared__ int wsum[16];
    int t = threadIdx.x;
    int wave = t >> 6, lane = t & 63;
    int base = blockIdx.x * ECHUNK;

    bool s2 = (t < (ECHUNK - 4096) / 4);        // 976
    uint4 dv0 = *(const uint4*)(dst + base + t * 4);
    uint4 sv0 = *(const uint4*)(src + base + t * 4);
    uint4 dv1 = make_uint4(0, 0, 0, 0), sv1 = make_uint4(0, 0, 0, 0);
    if (s2) {
        dv1 = *(const uint4*)(dst + base + 4096 + t * 4);
        sv1 = *(const uint4*)(src + base + 4096 + t * 4);
    }
    unsigned int dd[8] = {dv0.x, dv0.y, dv0.z, dv0.w, dv1.x, dv1.y, dv1.z, dv1.w};
    unsigned int ss[8] = {sv0.x, sv0.y, sv0.z, sv0.w, sv1.x, sv1.y, sv1.z, sv1.w};

    for (int k = t; k < NBUK; k += 1024) lh[k] = 0;
    __syncthreads();

#pragma unroll
    for (int r = 0; r < 4; r++) atomicAdd(&lh[dd[r] >> 8], 1);
    if (s2) {
#pragma unroll
        for (int r = 4; r < 8; r++) atomicAdd(&lh[dd[r] >> 8], 1);
    }
    __syncthreads();

    int v = (t < NBUK) ? lh[t] : 0;
    int x = v;
#pragma unroll
    for (int d0 = 1; d0 < 64; d0 <<= 1) {
        int y = __shfl_up(x, d0, 64);
        if (lane >= d0) x += y;
    }
    if (lane == 63) wsum[wave] = x;
    __syncthreads();
    if (wave == 0 && lane < 16) {
        int s = wsum[lane];
#pragma unroll
        for (int d0 = 1; d0 < 16; d0 <<= 1) {
            int y = __shfl_up(s, d0, 64);
            if (lane >= d0) s += y;
        }
        wsum[lane] = s;
    }
    __syncthreads();
    int excl = x - v + (wave ? wsum[wave - 1] : 0);
    if (t < NBUK) {
        lcur[t] = excl;
        int gb = v ? atomicAdd(&gcur[t], v) : 0;
        lh[t] = gb - excl;
    }
    __syncthreads();

#pragma unroll
    for (int r = 0; r < 4; r++) {
        int buk = dd[r] >> 8;
        int pos = atomicAdd(&lcur[buk], 1);
        stage[pos] = ((dd[r] & 255u) << 18) | ss[r];
        stageB[pos] = (unsigned short)buk;
    }
    if (s2) {
#pragma unroll
        for (int r = 4; r < 8; r++) {
            int buk = dd[r] >> 8;
            int pos = atomicAdd(&lcur[buk], 1);
            stage[pos] = ((dd[r] & 255u) << 18) | ss[r];
            stageB[pos] = (unsigned short)buk;
        }
    }
    __syncthreads();

    for (int e = t; e < ECHUNK; e += 1024) {
        int k = stageB[e];
        slab[(size_t)k * CAP + lh[k] + e] = stage[e];
    }
}

// ---- pDT (512 thr): per-bucket degree histogram (slab read ONCE, reg-staged, native
//      int LDS atomics) + dis + fused t1: hs1[i,:] = bf16((emb[ids[i]] @ W1) * dis[i]).
//      NO sort, NO meta — g kernels are entry-driven. ----
__global__ __launch_bounds__(512) void pDT(
        const unsigned int* __restrict__ slabR, const unsigned int* __restrict__ slabL,
        const int* __restrict__ gcurR, const int* __restrict__ gcurL,
        const int* __restrict__ idsR, const int* __restrict__ idsL,
        const float* __restrict__ emb, const float* __restrict__ W1,
        float* __restrict__ disR, float* __restrict__ disL,
        __hip_bfloat16* __restrict__ hs1R, __hip_bfloat16* __restrict__ hs1L) {
    int y = blockIdx.y;
    const unsigned int* slab = y ? slabL : slabR;
    const int* gcur = y ? gcurL : gcurR;
    const int* ids = y ? idsL : idsR;
    float* dis = y ? disL : disR;
    __hip_bfloat16* hs1 = y ? hs1L : hs1R;

    __shared__ int hcnt[BNODES];
    __shared__ float sW[D][D];
    int t = threadIdx.x;
    int b = blockIdx.x;
    if (t < 256) { sW[t >> 4][t & 15] = W1[t]; hcnt[t] = 0; }
    int cnt = gcur[b]; if (cnt > CAP) cnt = CAP;
    const unsigned int* sl = slab + (size_t)b * CAP;

    uint4 rv0 = make_uint4(0,0,0,0), rv1 = rv0, rv2 = rv0, rv3 = rv0, rv4 = rv0;
    {
        int i0 = t * 4;
        if (i0 < cnt)          rv0 = *(const uint4*)(sl + i0);
        if (i0 + 2048 < cnt)   rv1 = *(const uint4*)(sl + i0 + 2048);
        if (i0 + 4096 < cnt)   rv2 = *(const uint4*)(sl + i0 + 4096);
        if (i0 + 6144 < cnt)   rv3 = *(const uint4*)(sl + i0 + 6144);
        if (i0 + 8192 < cnt)   rv4 = *(const uint4*)(sl + i0 + 8192);
    }
    unsigned int rr[20] = {rv0.x, rv0.y, rv0.z, rv0.w, rv1.x, rv1.y, rv1.z, rv1.w,
                           rv2.x, rv2.y, rv2.z, rv2.w, rv3.x, rv3.y, rv3.z, rv3.w,
                           rv4.x, rv4.y, rv4.z, rv4.w};
    __syncthreads();

#pragma unroll
    for (int r = 0; r < 5; r++) {
        int i0 = t * 4 + r * 2048;
#pragma unroll
        for (int k = 0; k < 4; k++)
            if (i0 + k < cnt) atomicAdd(&hcnt[rr[r * 4 + k] >> 18], 1);
    }
    __syncthreads();

    // epilogue: dis + fused t1 (2 threads per node, 8 feats each)
    int tt = t >> 1, hf = t & 1;
    int node = (b << 8) + tt;
    if (node < N_NODES) {
        float di = rsqrtf((float)hcnt[tt] + 1.0f);
        if (hf == 0) dis[node] = di;
        const float4* er = (const float4*)(emb + (size_t)ids[node] * D);
        float4 e0 = er[0], e1 = er[1], e2 = er[2], e3 = er[3];
        float ex_[D] = {e0.x, e0.y, e0.z, e0.w, e1.x, e1.y, e1.z, e1.w,
                        e2.x, e2.y, e2.z, e2.w, e3.x, e3.y, e3.z, e3.w};
        int j0 = hf * 8;
        float o[8];
#pragma unroll
        for (int jj = 0; jj < 8; jj++) {
            float a = 0.f;
#pragma unroll
            for (int k = 0; k < D; k++) a += ex_[k] * sW[k][j0 + jj];
            o[jj] = a * di;
        }
        uint4 ov;
        __hip_bfloat162* q = (__hip_bfloat162*)&ov;
#pragma unroll
        for (int jj = 0; jj < 4; jj++)
            q[jj] = __float22bfloat162_rn(make_float2(o[2 * jj], o[2 * jj + 1]));
        *(uint4*)(hs1 + (size_t)node * D + j0) = ov;
    }
}

// ---- G1e: entry-driven gather (8 lanes/edge, 1 segment/edge), native ds_add_f32
//      accumulation (unsafeAtomicAdd), per-node epilogue: self+bias+relu+W2 -> hs2 ----
__global__ __launch_bounds__(256) void g1e_kernel(
        const unsigned int* __restrict__ slabR, const unsigned int* __restrict__ slabL,
        const int* __restrict__ gcurR, const int* __restrict__ gcurL,
        const __hip_bfloat16* __restrict__ hs1R, const __hip_bfloat16* __restrict__ hs1L,
        const float* __restrict__ disR, const float* __restrict__ disL,
        const float* __restrict__ b1, const float* __restrict__ W2,
        __hip_bfloat16* __restrict__ hs2R, __hip_bfloat16* __restrict__ hs2L) {
    int y = blockIdx.y;
    const unsigned int* slab = y ? slabL : slabR;
    const int* gcur = y ? gcurL : gcurR;
    const __hip_bfloat16* hs1 = y ? hs1L : hs1R;
    const float* dis = y ? disL : disR;
    __hip_bfloat16* hs2 = y ? hs2L : hs2R;

    __shared__ float acc[BNODES][D + 1];
    __shared__ float sW[D][D];
    int t = threadIdx.x;
    sW[t >> 4][t & 15] = W2[t];
    for (int idx = t; idx < BNODES * (D + 1); idx += 256)
        ((float*)acc)[idx] = 0.f;
    int b = blockIdx.x;
    int cnt = gcur[b]; if (cnt > CAP) cnt = CAP;
    const unsigned int* sl = slab + (size_t)b * CAP;
    __syncthreads();

    int jp = t & 7, eg = t >> 3;          // 32 edges per block step
    int ei = eg;
    for (; ei + 96 < cnt; ei += 128) {
        unsigned int r0 = __builtin_nontemporal_load(sl + ei);
        unsigned int r1 = __builtin_nontemporal_load(sl + ei + 32);
        unsigned int r2 = __builtin_nontemporal_load(sl + ei + 64);
        unsigned int r3 = __builtin_nontemporal_load(sl + ei + 96);
        float2 f0 = __bfloat1622float2(*(const __hip_bfloat162*)(hs1 + (size_t)(r0 & 0x3FFFFu) * D + 2 * jp));
        float2 f1 = __bfloat1622float2(*(const __hip_bfloat162*)(hs1 + (size_t)(r1 & 0x3FFFFu) * D + 2 * jp));
        float2 f2 = __bfloat1622float2(*(const __hip_bfloat162*)(hs1 + (size_t)(r2 & 0x3FFFFu) * D + 2 * jp));
        float2 f3 = __bfloat1622float2(*(const __hip_bfloat162*)(hs1 + (size_t)(r3 & 0x3FFFFu) * D + 2 * jp));
        unsafeAtomicAdd(&acc[r0 >> 18][2 * jp], f0.x);
        unsafeAtomicAdd(&acc[r0 >> 18][2 * jp + 1], f0.y);
        unsafeAtomicAdd(&acc[r1 >> 18][2 * jp], f1.x);
        unsafeAtomicAdd(&acc[r1 >> 18][2 * jp + 1], f1.y);
        unsafeAtomicAdd(&acc[r2 >> 18][2 * jp], f2.x);
        unsafeAtomicAdd(&acc[r2 >> 18][2 * jp + 1], f2.y);
        unsafeAtomicAdd(&acc[r3 >> 18][2 * jp], f3.x);
        unsafeAtomicAdd(&acc[r3 >> 18][2 * jp + 1], f3.y);
    }
    for (; ei < cnt; ei += 32) {
        unsigned int r0 = __builtin_nontemporal_load(sl + ei);
        float2 f0 = __bfloat1622float2(*(const __hip_bfloat162*)(hs1 + (size_t)(r0 & 0x3FFFFu) * D + 2 * jp));
        unsafeAtomicAdd(&acc[r0 >> 18][2 * jp], f0.x);
        unsafeAtomicAdd(&acc[r0 >> 18][2 * jp + 1], f0.y);
    }
    __syncthreads();

    int node = (b << 8) + t;
    if (node < N_NODES) {
        float di = dis[node];
        const uint4* hrow = (const uint4*)(hs1 + (size_t)node * D);
        uint4 s0 = hrow[0], s1 = hrow[1];
        float xv[D];
        const __hip_bfloat162* p0 = (const __hip_bfloat162*)&s0;
        const __hip_bfloat162* p1 = (const __hip_bfloat162*)&s1;
#pragma unroll
        for (int q = 0; q < 4; q++) {
            float2 f = __bfloat1622float2(p0[q]);
            xv[2 * q] = f.x; xv[2 * q + 1] = f.y;
            float2 g = __bfloat1622float2(p1[q]);
            xv[8 + 2 * q] = g.x; xv[8 + 2 * q + 1] = g.y;
        }
#pragma unroll
        for (int f = 0; f < D; f++)
            xv[f] = fmaxf((acc[t][f] + xv[f]) * di + b1[f], 0.f);
        uint4 o0, o1;
        __hip_bfloat162* q0 = (__hip_bfloat162*)&o0;
        __hip_bfloat162* q1 = (__hip_bfloat162*)&o1;
#pragma unroll
        for (int j = 0; j < D; j += 2) {
            float a0 = 0.f, a1 = 0.f;
#pragma unroll
            for (int k = 0; k < D; k++) {
                a0 += xv[k] * sW[k][j];
                a1 += xv[k] * sW[k][j + 1];
            }
            __hip_bfloat162 pk = __float22bfloat162_rn(make_float2(a0 * di, a1 * di));
            if (j < 8) q0[j >> 1] = pk; else q1[(j - 8) >> 1] = pk;
        }
        uint4* orow = (uint4*)(hs2 + (size_t)node * D);
        orow[0] = o0; orow[1] = o1;
    }
}

// ---- G2e: entry-driven gather layer2 + fused mean-pool partial reduction ----
__global__ __launch_bounds__(256) void g2e_kernel(
        const unsigned int* __restrict__ slabR, const unsigned int* __restrict__ slabL,
        const int* __restrict__ gcurR, const int* __restrict__ gcurL,
        const __hip_bfloat16* __restrict__ hs2R, const __hip_bfloat16* __restrict__ hs2L,
        const float* __restrict__ disR, const float* __restrict__ disL,
        const float* __restrict__ b2,
        const int* __restrict__ batR, const int* __restrict__ batL,
        float* __restrict__ sumsR, float* __restrict__ sumsL,
        float* __restrict__ cntR, float* __restrict__ cntL) {
    int y = blockIdx.y;
    const unsigned int* slab = y ? slabL : slabR;
    const int* gcur = y ? gcurL : gcurR;
    const __hip_bfloat16* hs2 = y ? hs2L : hs2R;
    const float* dis = y ? disL : disR;
    const int* batch = y ? batL : batR;
    float* sums = y ? sumsL : sumsR;
    float* cnt = y ? cntL : cntR;

    __shared__ float acc[BNODES][D + 1];
    __shared__ float gacc[16][D + 1];
    __shared__ int gcnt[16];
    int t = threadIdx.x;
    for (int idx = t; idx < BNODES * (D + 1); idx += 256)
        ((float*)acc)[idx] = 0.f;
    for (int idx = t; idx < 16 * (D + 1); idx += 256)
        ((float*)gacc)[idx] = 0.f;
    if (t < 16) gcnt[t] = 0;
    int b = blockIdx.x;
    int ec = gcur[b]; if (ec > CAP) ec = CAP;
    const unsigned int* sl = slab + (size_t)b * CAP;
    __syncthreads();

    int jp = t & 7, eg = t >> 3;
    int ei = eg;
    for (; ei + 96 < ec; ei += 128) {
        unsigned int r0 = __builtin_nontemporal_load(sl + ei);
        unsigned int r1 = __builtin_nontemporal_load(sl + ei + 32);
        unsigned int r2 = __builtin_nontemporal_load(sl + ei + 64);
        unsigned int r3 = __builtin_nontemporal_load(sl + ei + 96);
        float2 f0 = __bfloat1622float2(*(const __hip_bfloat162*)(hs2 + (size_t)(r0 & 0x3FFFFu) * D + 2 * jp));
        float2 f1 = __bfloat1622float2(*(const __hip_bfloat162*)(hs2 + (size_t)(r1 & 0x3FFFFu) * D + 2 * jp));
        float2 f2 = __bfloat1622float2(*(const __hip_bfloat162*)(hs2 + (size_t)(r2 & 0x3FFFFu) * D + 2 * jp));
        float2 f3 = __bfloat1622float2(*(const __hip_bfloat162*)(hs2 + (size_t)(r3 & 0x3FFFFu) * D + 2 * jp));
        unsafeAtomicAdd(&acc[r0 >> 18][2 * jp], f0.x);
        unsafeAtomicAdd(&acc[r0 >> 18][2 * jp + 1], f0.y);
        unsafeAtomicAdd(&acc[r1 >> 18][2 * jp], f1.x);
        unsafeAtomicAdd(&acc[r1 >> 18][2 * jp + 1], f1.y);
        unsafeAtomicAdd(&acc[r2 >> 18][2 * jp], f2.x);
        unsafeAtomicAdd(&acc[r2 >> 18][2 * jp + 1], f2.y);
        unsafeAtomicAdd(&acc[r3 >> 18][2 * jp], f3.x);
        unsafeAtomicAdd(&acc[r3 >> 18][2 * jp + 1], f3.y);
    }
    for (; ei < ec; ei += 32) {
        unsigned int r0 = __builtin_nontemporal_load(sl + ei);
        float2 f0 = __bfloat1622float2(*(const __hip_bfloat162*)(hs2 + (size_t)(r0 & 0x3FFFFu) * D + 2 * jp));
        unsafeAtomicAdd(&acc[r0 >> 18][2 * jp], f0.x);
        unsafeAtomicAdd(&acc[r0 >> 18][2 * jp + 1], f0.y);
    }
    __syncthreads();

    int b0 = batch[b << 8];
    int node = (b << 8) + t;
    if (node < N_NODES) {
        float di = dis[node];
        const uint4* hrow = (const uint4*)(hs2 + (size_t)node * D);
        uint4 s0 = hrow[0], s1 = hrow[1];
        float vv[D];
        const __hip_bfloat162* p0 = (const __hip_bfloat162*)&s0;
        const __hip_bfloat162* p1 = (const __hip_bfloat162*)&s1;
#pragma unroll
        for (int q = 0; q < 4; q++) {
            float2 f = __bfloat1622float2(p0[q]);
            vv[2 * q] = f.x; vv[2 * q + 1] = f.y;
            float2 g = __bfloat1622float2(p1[q]);
            vv[8 + 2 * q] = g.x; vv[8 + 2 * q + 1] = g.y;
        }
#pragma unroll
        for (int f = 0; f < D; f++)
            vv[f] = (acc[t][f] + vv[f]) * di + b2[f];
        int bi = batch[node];
        int slot = bi - b0;
        if (slot < 16) {
#pragma unroll
            for (int f = 0; f < D; f++) unsafeAtomicAdd(&gacc[slot][f], vv[f]);
            atomicAdd(&gcnt[slot], 1);
        } else {
#pragma unroll
            for (int f = 0; f < D; f++) atomicAdd(&sums[(size_t)bi * D + f], vv[f]);
            atomicAdd(&cnt[bi], 1.0f);
        }
    }
    __syncthreads();
    int s = t >> 4, f = t & 15;
    int c = gcnt[s];
    if (c > 0) {
        atomicAdd(&sums[(size_t)(b0 + s) * D + f], gacc[s][f]);
        if (f == 0) atomicAdd(&cnt[b0 + s], (float)c);
    }
}

// ---- final FC ----
__global__ void final_kernel(const float* __restrict__ rs, const float* __restrict__ rc,
                             const float* __restrict__ ls, const float* __restrict__ lc,
                             const float* __restrict__ fcW, const float* __restrict__ fcb,
                             float* __restrict__ out) {
    int b = blockIdx.x * blockDim.x + threadIdx.x;
    if (b >= N_GRAPHS) return;
    float hc[2 * D];
    float rn = fmaxf(rc[b], 1.f), ln = fmaxf(lc[b], 1.f);
#pragma unroll
    for (int j = 0; j < D; j++) {
        hc[j]     = rs[b * D + j] / rn;
        hc[D + j] = ls[b * D + j] / ln;
    }
#pragma unroll
    for (int c = 0; c < 6; c++) {
        float acc = fcb[c];
#pragma unroll
        for (int j = 0; j < 2 * D; j++) acc += hc[j] * fcW[c * 2 * D + j];
        if (c < 3) out[b * 3 + c] = acc;
        else       out[N_GRAPHS * 3 + b * 3 + (c - 3)] = acc;
    }
}

extern "C" void kernel_launch(void* const* d_in, const int* in_sizes, int n_in,
                              void* d_out, int out_size, void* d_ws, size_t ws_size,
                              hipStream_t stream) {
    const float* emb = (const float*)d_in[0];
    const float* W1  = (const float*)d_in[1];
    const float* b1  = (const float*)d_in[2];
    const float* W2  = (const float*)d_in[3];
    const float* b2  = (const float*)d_in[4];
    const float* fcW = (const float*)d_in[5];
    const float* fcb = (const float*)d_in[6];
    const int* rx = (const int*)d_in[7];
    const int* re = (const int*)d_in[8];
    const int* rb = (const int*)d_in[9];
    const int* lx = (const int*)d_in[10];
    const int* le = (const int*)d_in[11];
    const int* lb = (const int*)d_in[12];
    float* out = (float*)d_out;

    char* w = (char*)d_ws;
    unsigned int* slabR = (unsigned int*)w;    w += (size_t)NBUK * CAP * 4;
    unsigned int* slabL = (unsigned int*)w;    w += (size_t)NBUK * CAP * 4;
    __hip_bfloat16* hs1R = (__hip_bfloat16*)w; w += (size_t)N_NODES * D * 2;
    __hip_bfloat16* hs1L = (__hip_bfloat16*)w; w += (size_t)N_NODES * D * 2;
    __hip_bfloat16* hs2R = (__hip_bfloat16*)w; w += (size_t)N_NODES * D * 2;
    __hip_bfloat16* hs2L = (__hip_bfloat16*)w; w += (size_t)N_NODES * D * 2;
    float* disR = (float*)w;                   w += (size_t)N_NODES * 4;
    float* disL = (float*)w;                   w += (size_t)N_NODES * 4;
    // zero-init region: gcurR, gcurL, sums0, cnt0, sums1, cnt1 (single memset)
    char* zbase = w;
    int* gcurR = (int*)w;                      w += (size_t)NBUK * 4;
    int* gcurL = (int*)w;                      w += (size_t)NBUK * 4;
    float* sums0 = (float*)w;                  w += (size_t)N_GRAPHS * D * 4;
    float* cnt0  = (float*)w;                  w += (size_t)N_GRAPHS * 4;
    float* sums1 = (float*)w;                  w += (size_t)N_GRAPHS * D * 4;
    float* cnt1  = (float*)w;                  w += (size_t)N_GRAPHS * 4;
    size_t zsize = (size_t)(w - zbase);

    const int* srcR = re;  const int* dstR = re + NEDGE;
    const int* srcL = le;  const int* dstL = le + NEDGE;

    hipMemsetAsync(zbase, 0, zsize, stream);

    // ---- CSR build: reg-staged direct-append; NO within-bucket sort ----
    pA<<<dim3(NCH, 2), 1024, 0, stream>>>(srcR, dstR, srcL, dstL,
                                          slabR, slabL, gcurR, gcurL);
    pDT<<<dim3(NBUK, 2), 512, 0, stream>>>(slabR, slabL, gcurR, gcurL,
                                           rx, lx, emb, W1, disR, disL, hs1R, hs1L);

    // ---- entry-driven GCN pipeline (native ds_add_f32 accumulation) ----
    g1e_kernel<<<dim3(NBUK, 2), 256, 0, stream>>>(slabR, slabL, gcurR, gcurL,
                                                  hs1R, hs1L, disR, disL, b1, W2,
                                                  hs2R, hs2L);
    g2e_kernel<<<dim3(NBUK, 2), 256, 0, stream>>>(slabR, slabL, gcurR, gcurL,
                                                  hs2R, hs2L, disR, disL, b2, rb, lb,
                                                  sums0, sums1, cnt0, cnt1);
    final_kernel<<<(N_GRAPHS + 255) / 256, 256, 0, stream>>>(
        sums0, cnt0, sums1, cnt1, fcW, fcb, out);
}

// Round 11
// 472.017 us; speedup vs baseline: 5.5076x; 5.5076x over previous
//
#include <hip/hip_runtime.h>
#include <hip/hip_bf16.h>

#define N_NODES 200000
#define N_GRAPHS 1024
#define D 16
#define NEDGE 6400000

#define BNODES 256                 // nodes per bucket: bucket = dst >> 8
#define NBUK 782                   // ceil(200000/256)
#define NCH 800                    // edge chunks
#define ECHUNK 8000                // NEDGE / NCH (exact)
#define CAP 9216                   // bucket slab capacity (mean 8192, sd ~90 -> 11 sigma)
#define GHALF 6250                 // gather blocks per protein: 32 nodes x 8 lanes

// ---- pA (fused R+L): reg-staged chunk sort, SINGLE LDS-atomic pass.
//      The count atomicAdd's return value IS the edge's intra-bucket rank;
//      placement is atomic-free: pos = excl[buk] + rank. ----
__global__ __launch_bounds__(1024) void pA(
        const int* __restrict__ srcR, const int* __restrict__ dstR,
        const int* __restrict__ srcL, const int* __restrict__ dstL,
        unsigned int* __restrict__ slabR, unsigned int* __restrict__ slabL,
        int* __restrict__ gcurR, int* __restrict__ gcurL) {
    const int* src = blockIdx.y ? srcL : srcR;
    const int* dst = blockIdx.y ? dstL : dstR;
    unsigned int* slab = blockIdx.y ? slabL : slabR;
    int* gcur = blockIdx.y ? gcurL : gcurR;

    __shared__ unsigned int stage[ECHUNK];      // 32 KB
    __shared__ unsigned short stageB[ECHUNK];   // 16 KB
    __shared__ int lh[NBUK];                    // counts -> writeback offset (gb-excl)
    __shared__ int lex[NBUK];                   // bucket excl base for placement
    __shared__ int wsum[16];
    int t = threadIdx.x;
    int wave = t >> 6, lane = t & 63;
    int base = blockIdx.x * ECHUNK;

    bool s2 = (t < (ECHUNK - 4096) / 4);        // 976
    uint4 dv0 = *(const uint4*)(dst + base + t * 4);
    uint4 sv0 = *(const uint4*)(src + base + t * 4);
    uint4 dv1 = make_uint4(0, 0, 0, 0), sv1 = make_uint4(0, 0, 0, 0);
    if (s2) {
        dv1 = *(const uint4*)(dst + base + 4096 + t * 4);
        sv1 = *(const uint4*)(src + base + 4096 + t * 4);
    }
    unsigned int dd[8] = {dv0.x, dv0.y, dv0.z, dv0.w, dv1.x, dv1.y, dv1.z, dv1.w};
    unsigned int ss[8] = {sv0.x, sv0.y, sv0.z, sv0.w, sv1.x, sv1.y, sv1.z, sv1.w};
    int rk[8];

    for (int k = t; k < NBUK; k += 1024) lh[k] = 0;
    __syncthreads();

    // count from registers, capturing intra-bucket ranks
#pragma unroll
    for (int r = 0; r < 4; r++) rk[r] = atomicAdd(&lh[dd[r] >> 8], 1);
    if (s2) {
#pragma unroll
        for (int r = 4; r < 8; r++) rk[r] = atomicAdd(&lh[dd[r] >> 8], 1);
    }
    __syncthreads();

    // block exclusive scan of lh (16 waves)
    int v = (t < NBUK) ? lh[t] : 0;
    int x = v;
#pragma unroll
    for (int d0 = 1; d0 < 64; d0 <<= 1) {
        int y = __shfl_up(x, d0, 64);
        if (lane >= d0) x += y;
    }
    if (lane == 63) wsum[wave] = x;
    __syncthreads();
    if (wave == 0 && lane < 16) {
        int s = wsum[lane];
#pragma unroll
        for (int d0 = 1; d0 < 16; d0 <<= 1) {
            int y = __shfl_up(s, d0, 64);
            if (lane >= d0) s += y;
        }
        wsum[lane] = s;
    }
    __syncthreads();
    int excl = x - v + (wave ? wsum[wave - 1] : 0);
    if (t < NBUK) {
        lex[t] = excl;
        int gb = v ? atomicAdd(&gcur[t], v) : 0;   // allocate this chunk's run
        lh[t] = gb - excl;                          // global offset = lh[buk] + staged_pos
    }
    __syncthreads();

    // place from registers — NO atomics (pos = excl + rank)
#pragma unroll
    for (int r = 0; r < 4; r++) {
        int buk = dd[r] >> 8;
        int pos = lex[buk] + rk[r];
        stage[pos] = ((dd[r] & 255u) << 18) | ss[r];
        stageB[pos] = (unsigned short)buk;
    }
    if (s2) {
#pragma unroll
        for (int r = 4; r < 8; r++) {
            int buk = dd[r] >> 8;
            int pos = lex[buk] + rk[r];
            stage[pos] = ((dd[r] & 255u) << 18) | ss[r];
            stageB[pos] = (unsigned short)buk;
        }
    }
    __syncthreads();

    // coalesced writeback of per-bucket runs
    for (int e = t; e < ECHUNK; e += 1024) {
        int k = stageB[e];
        slab[(size_t)k * CAP + lh[k] + e] = stage[e];
    }
}

// ---- pB2 (512 thr): reg-staged in-place per-bucket counting sort, SINGLE
//      LDS-atomic pass (rank capture), FUSED with the t1 transform epilogue:
//      hs1[i,:] = bf16((emb[ids[i]] @ W1) * dis[i]) ----
__global__ __launch_bounds__(512) void pB2(
        unsigned int* __restrict__ slabR, unsigned int* __restrict__ slabL,
        const int* __restrict__ gcurR, const int* __restrict__ gcurL,
        const int* __restrict__ idsR, const int* __restrict__ idsL,
        const float* __restrict__ emb, const float* __restrict__ W1,
        int2* __restrict__ metaR, int2* __restrict__ metaL,
        float* __restrict__ disR, float* __restrict__ disL,
        __hip_bfloat16* __restrict__ hs1R, __hip_bfloat16* __restrict__ hs1L) {
    int y = blockIdx.y;
    unsigned int* slab = y ? slabL : slabR;
    const int* gcur = y ? gcurL : gcurR;
    const int* ids = y ? idsL : idsR;
    int2* meta = y ? metaL : metaR;
    float* dis = y ? disL : disR;
    __hip_bfloat16* hs1 = y ? hs1L : hs1R;

    __shared__ unsigned int sout[CAP];       // 36.9 KB
    __shared__ int hcnt[BNODES], hoff[BNODES];
    __shared__ float sW[D][D];
    __shared__ int wtot[8];
    int t = threadIdx.x;
    int lane = t & 63, wave = t >> 6;        // 8 waves
    int b = blockIdx.x;
    if (t < 256) { sW[t >> 4][t & 15] = W1[t]; hcnt[t] = 0; }
    int cnt = gcur[b]; if (cnt > CAP) cnt = CAP;   // statistically unreachable
    unsigned int* sl = slab + (size_t)b * CAP;

    // reg stage: up to 20 entries/thread (5 uint4), slab read ONCE
    uint4 rv0 = make_uint4(0,0,0,0), rv1 = rv0, rv2 = rv0, rv3 = rv0, rv4 = rv0;
    {
        int i0 = t * 4;
        if (i0 < cnt)          rv0 = *(const uint4*)(sl + i0);
        if (i0 + 2048 < cnt)   rv1 = *(const uint4*)(sl + i0 + 2048);
        if (i0 + 4096 < cnt)   rv2 = *(const uint4*)(sl + i0 + 4096);
        if (i0 + 6144 < cnt)   rv3 = *(const uint4*)(sl + i0 + 6144);
        if (i0 + 8192 < cnt)   rv4 = *(const uint4*)(sl + i0 + 8192);
    }
    unsigned int rr[20] = {rv0.x, rv0.y, rv0.z, rv0.w, rv1.x, rv1.y, rv1.z, rv1.w,
                           rv2.x, rv2.y, rv2.z, rv2.w, rv3.x, rv3.y, rv3.z, rv3.w,
                           rv4.x, rv4.y, rv4.z, rv4.w};
    int rk[20];
    __syncthreads();

    // count from registers, capturing intra-node ranks
#pragma unroll
    for (int r = 0; r < 5; r++) {
        int i0 = t * 4 + r * 2048;
#pragma unroll
        for (int k = 0; k < 4; k++)
            if (i0 + k < cnt) rk[r * 4 + k] = atomicAdd(&hcnt[rr[r * 4 + k] >> 18], 1);
    }
    __syncthreads();

    // exclusive scan over 256 node counts (first 4 waves)
    int v2 = (t < 256) ? hcnt[t] : 0;
    int x2 = v2;
#pragma unroll
    for (int d0 = 1; d0 < 64; d0 <<= 1) {
        int yy = __shfl_up(x2, d0, 64);
        if (lane >= d0) x2 += yy;
    }
    if (t < 256 && lane == 63) wtot[wave] = x2;
    __syncthreads();
    if (t < 256) {
        int pre2 = 0;
        for (int w2 = 0; w2 < wave; w2++) pre2 += wtot[w2];
        hoff[t] = x2 - v2 + pre2;
    }
    __syncthreads();

    // place from registers — NO atomics (pos = hoff + rank)
#pragma unroll
    for (int r = 0; r < 5; r++) {
        int i0 = t * 4 + r * 2048;
#pragma unroll
        for (int k = 0; k < 4; k++)
            if (i0 + k < cnt) {
                unsigned int e = rr[r * 4 + k];
                sout[hoff[e >> 18] + rk[r * 4 + k]] = e & 0x3FFFFu;
            }
    }
    __syncthreads();

    // in-place sorted writeback
    for (int i = t; i < cnt; i += 512) sl[i] = sout[i];   // coalesced

    // epilogue: meta/dis + fused t1 (2 threads per node, 8 feats each)
    int tt = t >> 1, hf = t & 1;
    int node = (b << 8) + tt;
    if (node < N_NODES) {
        int hc = hcnt[tt];
        float di = rsqrtf((float)hc + 1.0f);
        int gb = b * CAP;
        if (hf == 0) {
            meta[node] = make_int2(gb + hoff[tt], gb + hoff[tt] + hc);
            dis[node] = di;
        }
        const float4* er = (const float4*)(emb + (size_t)ids[node] * D);
        float4 e0 = er[0], e1 = er[1], e2 = er[2], e3 = er[3];
        float ex_[D] = {e0.x, e0.y, e0.z, e0.w, e1.x, e1.y, e1.z, e1.w,
                        e2.x, e2.y, e2.z, e2.w, e3.x, e3.y, e3.z, e3.w};
        int j0 = hf * 8;
        float o[8];
#pragma unroll
        for (int jj = 0; jj < 8; jj++) {
            float a = 0.f;
#pragma unroll
            for (int k = 0; k < D; k++) a += ex_[k] * sW[k][j0 + jj];
            o[jj] = a * di;
        }
        uint4 ov;
        __hip_bfloat162* q = (__hip_bfloat162*)&ov;
#pragma unroll
        for (int jj = 0; jj < 4; jj++)
            q[jj] = __float22bfloat162_rn(make_float2(o[2 * jj], o[2 * jj + 1]));
        *(uint4*)(hs1 + (size_t)node * D + j0) = ov;
    }
}

// ---- G1: gather layer1 + relu + transform2 -> hs2. 32 nodes/block, 8 lanes/node. ----
__global__ __launch_bounds__(256) void g1_kernel(
        const int2* __restrict__ metaR, const int2* __restrict__ metaL,
        const unsigned int* __restrict__ csrR, const unsigned int* __restrict__ csrL,
        const __hip_bfloat16* __restrict__ hs1R, const __hip_bfloat16* __restrict__ hs1L,
        const float* __restrict__ disR, const float* __restrict__ disL,
        const float* __restrict__ b1, const float* __restrict__ W2,
        __hip_bfloat16* __restrict__ hs2R, __hip_bfloat16* __restrict__ hs2L) {
    int half = (blockIdx.x >= GHALF);
    int bx = blockIdx.x - (half ? GHALF : 0);
    const int2* meta = half ? metaL : metaR;
    const unsigned int* csr = half ? csrL : csrR;
    const __hip_bfloat16* hs1 = half ? hs1L : hs1R;
    const float* dis = half ? disL : disR;
    __hip_bfloat16* hs2 = half ? hs2L : hs2R;

    __shared__ float sW[D][D];
    __shared__ float sx[32][D + 1];
    int t = threadIdx.x;
    int jp = t & 7, g = t >> 3;
    sW[t >> 4][t & 15] = W2[t];
    int i = (bx << 5) + g;
    int2 be = meta[i];
    float2 acc = __bfloat1622float2(
        *(const __hip_bfloat162*)(hs1 + (size_t)i * D + 2 * jp));
    int e = be.x, end = be.y;
    for (; e + 8 <= end; e += 8) {
        int my = (int)csr[e + jp];
#pragma unroll
        for (int n = 0; n < 8; n++) {
            int s = __shfl(my, n, 8);
            float2 f = __bfloat1622float2(
                *(const __hip_bfloat162*)(hs1 + (size_t)s * D + 2 * jp));
            acc.x += f.x; acc.y += f.y;
        }
    }
    for (; e < end; e++) {
        int s = csr[e];
        float2 f = __bfloat1622float2(
            *(const __hip_bfloat162*)(hs1 + (size_t)s * D + 2 * jp));
        acc.x += f.x; acc.y += f.y;
    }
    float di = dis[i];
    sx[g][2 * jp]     = fmaxf(acc.x * di + b1[2 * jp], 0.f);
    sx[g][2 * jp + 1] = fmaxf(acc.y * di + b1[2 * jp + 1], 0.f);
    __syncthreads();
    float a0 = 0.f, a1 = 0.f;
#pragma unroll
    for (int k = 0; k < D; k++) {
        float xv = sx[g][k];
        a0 += xv * sW[k][2 * jp];
        a1 += xv * sW[k][2 * jp + 1];
    }
    *(__hip_bfloat162*)(hs2 + (size_t)i * D + 2 * jp) =
        __float22bfloat162_rn(make_float2(a0 * di, a1 * di));
}

// ---- G2: gather layer2 + fused mean-pool partial reduction ----
__global__ __launch_bounds__(256) void g2_kernel(
        const int2* __restrict__ metaR, const int2* __restrict__ metaL,
        const unsigned int* __restrict__ csrR, const unsigned int* __restrict__ csrL,
        const __hip_bfloat16* __restrict__ hs2R, const __hip_bfloat16* __restrict__ hs2L,
        const float* __restrict__ disR, const float* __restrict__ disL,
        const float* __restrict__ b2,
        const int* __restrict__ batR, const int* __restrict__ batL,
        float* __restrict__ sumsR, float* __restrict__ sumsL,
        float* __restrict__ cntR, float* __restrict__ cntL) {
    int half = (blockIdx.x >= GHALF);
    int bx = blockIdx.x - (half ? GHALF : 0);
    const int2* meta = half ? metaL : metaR;
    const unsigned int* csr = half ? csrL : csrR;
    const __hip_bfloat16* hs2 = half ? hs2L : hs2R;
    const float* dis = half ? disL : disR;
    const int* batch = half ? batL : batR;
    float* sums = half ? sumsL : sumsR;
    float* cnt = half ? cntL : cntR;

    __shared__ float sv[32][D + 1];
    __shared__ int sb[32];
    int t = threadIdx.x;
    int jp = t & 7, g = t >> 3;
    int i = (bx << 5) + g;
    int2 be = meta[i];
    float2 acc = __bfloat1622float2(
        *(const __hip_bfloat162*)(hs2 + (size_t)i * D + 2 * jp));
    int e = be.x, end = be.y;
    for (; e + 8 <= end; e += 8) {
        int my = (int)csr[e + jp];
#pragma unroll
        for (int n = 0; n < 8; n++) {
            int s = __shfl(my, n, 8);
            float2 f = __bfloat1622float2(
                *(const __hip_bfloat162*)(hs2 + (size_t)s * D + 2 * jp));
            acc.x += f.x; acc.y += f.y;
        }
    }
    for (; e < end; e++) {
        int s = csr[e];
        float2 f = __bfloat1622float2(
            *(const __hip_bfloat162*)(hs2 + (size_t)s * D + 2 * jp));
        acc.x += f.x; acc.y += f.y;
    }
    float di = dis[i];
    int bi = batch[i];
    sv[g][2 * jp]     = acc.x * di + b2[2 * jp];
    sv[g][2 * jp + 1] = acc.y * di + b2[2 * jp + 1];
    if (jp == 0) sb[g] = bi;
    __syncthreads();
    bool runend = (g == 31) || (sb[g + 1] != bi);
    if (runend) {
        float s0 = 0.f, s1 = 0.f;
        int gg = g;
        while (gg >= 0 && sb[gg] == bi) { s0 += sv[gg][2 * jp]; s1 += sv[gg][2 * jp + 1]; gg--; }
        atomicAdd(&sums[bi * D + 2 * jp], s0);
        atomicAdd(&sums[bi * D + 2 * jp + 1], s1);
        if (jp == 0) atomicAdd(&cnt[bi], (float)(g - gg));
    }
}

// ---- final FC ----
__global__ void final_kernel(const float* __restrict__ rs, const float* __restrict__ rc,
                             const float* __restrict__ ls, const float* __restrict__ lc,
                             const float* __restrict__ fcW, const float* __restrict__ fcb,
                             float* __restrict__ out) {
    int b = blockIdx.x * blockDim.x + threadIdx.x;
    if (b >= N_GRAPHS) return;
    float hc[2 * D];
    float rn = fmaxf(rc[b], 1.f), ln = fmaxf(lc[b], 1.f);
#pragma unroll
    for (int j = 0; j < D; j++) {
        hc[j]     = rs[b * D + j] / rn;
        hc[D + j] = ls[b * D + j] / ln;
    }
#pragma unroll
    for (int c = 0; c < 6; c++) {
        float acc = fcb[c];
#pragma unroll
        for (int j = 0; j < 2 * D; j++) acc += hc[j] * fcW[c * 2 * D + j];
        if (c < 3) out[b * 3 + c] = acc;
        else       out[N_GRAPHS * 3 + b * 3 + (c - 3)] = acc;
    }
}

extern "C" void kernel_launch(void* const* d_in, const int* in_sizes, int n_in,
                              void* d_out, int out_size, void* d_ws, size_t ws_size,
                              hipStream_t stream) {
    const float* emb = (const float*)d_in[0];
    const float* W1  = (const float*)d_in[1];
    const float* b1  = (const float*)d_in[2];
    const float* W2  = (const float*)d_in[3];
    const float* b2  = (const float*)d_in[4];
    const float* fcW = (const float*)d_in[5];
    const float* fcb = (const float*)d_in[6];
    const int* rx = (const int*)d_in[7];
    const int* re = (const int*)d_in[8];
    const int* rb = (const int*)d_in[9];
    const int* lx = (const int*)d_in[10];
    const int* le = (const int*)d_in[11];
    const int* lb = (const int*)d_in[12];
    float* out = (float*)d_out;

    char* w = (char*)d_ws;
    unsigned int* slabR = (unsigned int*)w;    w += (size_t)NBUK * CAP * 4;
    unsigned int* slabL = (unsigned int*)w;    w += (size_t)NBUK * CAP * 4;
    __hip_bfloat16* hs1R = (__hip_bfloat16*)w; w += (size_t)N_NODES * D * 2;
    __hip_bfloat16* hs1L = (__hip_bfloat16*)w; w += (size_t)N_NODES * D * 2;
    __hip_bfloat16* hs2R = (__hip_bfloat16*)w; w += (size_t)N_NODES * D * 2;
    __hip_bfloat16* hs2L = (__hip_bfloat16*)w; w += (size_t)N_NODES * D * 2;
    int2* metaR = (int2*)w;                    w += (size_t)N_NODES * 8;
    int2* metaL = (int2*)w;                    w += (size_t)N_NODES * 8;
    float* disR = (float*)w;                   w += (size_t)N_NODES * 4;
    float* disL = (float*)w;                   w += (size_t)N_NODES * 4;
    // zero-init region: gcurR, gcurL, sums0, cnt0, sums1, cnt1 (single memset)
    char* zbase = w;
    int* gcurR = (int*)w;                      w += (size_t)NBUK * 4;
    int* gcurL = (int*)w;                      w += (size_t)NBUK * 4;
    float* sums0 = (float*)w;                  w += (size_t)N_GRAPHS * D * 4;
    float* cnt0  = (float*)w;                  w += (size_t)N_GRAPHS * 4;
    float* sums1 = (float*)w;                  w += (size_t)N_GRAPHS * D * 4;
    float* cnt1  = (float*)w;                  w += (size_t)N_GRAPHS * 4;
    size_t zsize = (size_t)(w - zbase);

    const int* srcR = re;  const int* dstR = re + NEDGE;
    const int* srcL = le;  const int* dstL = le + NEDGE;

    hipMemsetAsync(zbase, 0, zsize, stream);

    // ---- CSR build: reg-staged direct-append + rank-based in-place sort (+fused t1) ----
    pA<<<dim3(NCH, 2), 1024, 0, stream>>>(srcR, dstR, srcL, dstL,
                                          slabR, slabL, gcurR, gcurL);
    pB2<<<dim3(NBUK, 2), 512, 0, stream>>>(slabR, slabL, gcurR, gcurL,
                                           rx, lx, emb, W1,
                                           metaR, metaL, disR, disL, hs1R, hs1L);

    // ---- fused GCN pipeline ----
    g1_kernel<<<2 * GHALF, 256, 0, stream>>>(metaR, metaL, slabR, slabL,
                                             hs1R, hs1L, disR, disL, b1, W2, hs2R, hs2L);
    g2_kernel<<<2 * GHALF, 256, 0, stream>>>(metaR, metaL, slabR, slabL,
                                             hs2R, hs2L, disR, disL, b2, rb, lb,
                                             sums0, sums1, cnt0, cnt1);
    final_kernel<<<(N_GRAPHS + 255) / 256, 256, 0, stream>>>(
        sums0, cnt0, sums1, cnt1, fcW, fcb, out);
}